// Round 3
// baseline (8829.308 us; speedup 1.0000x reference)
//
#include <hip/hip_runtime.h>
#include <cstdint>
#include <cmath>

typedef unsigned short u16;
typedef unsigned long long u64;
typedef __attribute__((ext_vector_type(8))) short short8;
typedef __attribute__((ext_vector_type(4))) float f32x4;

#define SEQ 1024
#define HD 1024
#define GD 4096
#define NB 8
#define MROWS 8192   // NB*SEQ
#define NWG 128
#define NU 8         // hidden units per workgroup

__device__ __forceinline__ u16 f2bf(float f) {
  union { float f; uint32_t u; } c; c.f = f;
  uint32_t u = c.u;
  uint32_t r = (u + 0x7fffu + ((u >> 16) & 1u)) >> 16;
  return (u16)r;
}
__device__ __forceinline__ float bf2f(u16 h) {
  union { uint32_t u; float f; } c; c.u = ((uint32_t)h) << 16;
  return c.f;
}

// ---------------- fp32 -> bf16 convert ----------------
__global__ void k_tobf16(const float* __restrict__ in, u16* __restrict__ out, long n) {
  long i = ((long)blockIdx.x * 256L + threadIdx.x) * 4;
  long st = (long)gridDim.x * 1024L;
  for (; i < n; i += st) {
    float4 v = *(const float4*)(in + i);
    ushort4 o;
    o.x = f2bf(v.x); o.y = f2bf(v.y); o.z = f2bf(v.z); o.w = f2bf(v.w);
    *(ushort4*)(out + i) = o;
  }
}

// ---------------- bf16 MFMA GEMM: C[m][n] = sum_k A[m][k]*Bw[n][k] (+epilogue) ----
// MODE 0: outb[(t*8+b)*4096 + col] = bf16(acc + bias[n])   (t-major relayout for scan)
// MODE 1: outf = gelu(acc + bias[n]) + res[m][n]           (exact gelu)
template<int MODE>
__global__ __launch_bounds__(256, 1) void k_gemm(
    const u16* __restrict__ A, const u16* __restrict__ Bw,
    const float* __restrict__ bias, const float* __restrict__ res,
    u16* __restrict__ outb, float* __restrict__ outf, int N, int K)
{
  __shared__ u16 As[128][40];
  __shared__ u16 Bs[128][40];
  const int tid = threadIdx.x;
  const int wid = tid >> 6, lane = tid & 63;
  const int wm = wid >> 1, wn = wid & 1;
  const int r = lane & 15, q = lane >> 4;
  const long m0 = (long)blockIdx.y * 128, n0 = (long)blockIdx.x * 128;
  const int srow = tid >> 1, sseg = (tid & 1) * 16;

  f32x4 acc[4][4];
#pragma unroll
  for (int i = 0; i < 4; ++i)
#pragma unroll
    for (int j = 0; j < 4; ++j) acc[i][j] = (f32x4){0.f, 0.f, 0.f, 0.f};

  const u16* ag = A + (m0 + srow) * (long)K + sseg;
  const u16* bg = Bw + (n0 + srow) * (long)K + sseg;

  for (int k0 = 0; k0 < K; k0 += 32) {
    short8 av0 = *(const short8*)(ag + k0);
    short8 av1 = *(const short8*)(ag + k0 + 8);
    short8 bv0 = *(const short8*)(bg + k0);
    short8 bv1 = *(const short8*)(bg + k0 + 8);
    __syncthreads();
    *(short8*)&As[srow][sseg]     = av0;
    *(short8*)&As[srow][sseg + 8] = av1;
    *(short8*)&Bs[srow][sseg]     = bv0;
    *(short8*)&Bs[srow][sseg + 8] = bv1;
    __syncthreads();
    short8 bfr[4];
#pragma unroll
    for (int ni = 0; ni < 4; ++ni)
      bfr[ni] = *(const short8*)&Bs[wn * 64 + ni * 16 + r][q * 8];
#pragma unroll
    for (int mi = 0; mi < 4; ++mi) {
      short8 afr = *(const short8*)&As[wm * 64 + mi * 16 + r][q * 8];
#pragma unroll
      for (int ni = 0; ni < 4; ++ni)
        acc[mi][ni] = __builtin_amdgcn_mfma_f32_16x16x32_bf16(afr, bfr[ni], acc[mi][ni], 0, 0, 0);
    }
  }

#pragma unroll
  for (int mi = 0; mi < 4; ++mi)
#pragma unroll
    for (int ni = 0; ni < 4; ++ni) {
      long col = n0 + wn * 64 + ni * 16 + r;
      float bc = bias[col];
#pragma unroll
      for (int rr = 0; rr < 4; ++rr) {
        long row = m0 + wm * 64 + mi * 16 + q * 4 + rr;
        float v = acc[mi][ni][rr] + bc;
        if (MODE == 0) {
          long b = row >> 10, t = row & 1023;
          outb[((t * 8 + b) << 12) + col] = f2bf(v);
        } else {
          float ge = 0.5f * v * (1.0f + erff(v * 0.70710678118654752f));
          outf[row * N + col] = ge + res[row * N + col];
        }
      }
    }
}

// ---------------- persistent sLSTM scan ----------------
// 128 WGs x 512 threads, 1/CU. WG wg owns hidden units [wg*8, wg*8+8) for all
// 8 batches. h exchange via SELF-VALIDATING tagged words: u32 = (tag<<16)|h_bf16,
// fire-and-forget agent stores; readers poll the data itself (per-u64 re-poll).
// No central flag, no store-ack wait, no cache flush.
__global__ __launch_bounds__(512, 1) void k_scan(
    const u16* __restrict__ xp, const u16* __restrict__ Rb,
    u16* __restrict__ hseq, uint32_t* __restrict__ hxT, int tagbase)
{
  __shared__ u16 wgt[32 * 1024];      // [c][k], chunk-XOR-swizzled
  __shared__ u16 hA[16 * 1024];       // [row][k], rows 8..15 stay zero
  __shared__ float Dred[8][256];      // per-wave 16x16 partials
  __shared__ float xpf[2][NB][32];    // prefetched xp, [buf][b][g*8+u]
  __shared__ u16 hhist[32 * 64];      // [t&31][b*8+u] staged h for hseq dump

  const int tid = threadIdx.x;
  const int wg = blockIdx.x;
  const int wid = tid >> 6, lane = tid & 63;
  const int r = lane & 15, q = lane >> 4;

  // stage weights: c = tid>>4 (0..31), seg = tid&15; row c -> R row g*1024+wg*8+u
  {
    const int c = tid >> 4, seg = tid & 15;
    const int u = c >> 2, g = c & 3;
    const u16* src = Rb + ((long)(g * HD + wg * NU + u)) * HD + seg * 64;
#pragma unroll
    for (int j = 0; j < 8; ++j) {
      short8 v = *(const short8*)(src + j * 8);
      int chunk = seg * 8 + j;
      *(short8*)&wgt[c * 1024 + ((chunk ^ (c & 7)) << 3)] = v;
    }
  }
  // zero hA
#pragma unroll
  for (int j = 0; j < 4; ++j)
    *(short8*)&hA[(tid * 4 + j) * 8] = (short8){0, 0, 0, 0, 0, 0, 0, 0};

  // prologue: xp[t=0]  (t-major layout: ((t*8+b)<<12) + g*1024 + wg*8)
  if (tid >= 64 && tid < 96) {
    const int b = (tid - 64) >> 2, g = (tid - 64) & 3;
    short8 v = *(const short8*)(xp + ((long)(0 * 8 + b) << 12) + g * HD + wg * NU);
#pragma unroll
    for (int u = 0; u < 8; ++u) xpf[0][b][g * 8 + u] = bf2f(((u16*)&v)[u]);
  }
  __syncthreads();

  float c_s = 0.f, n_s = 0.f, m_s = 0.f;

  for (int t = 0; t < SEQ; ++t) {
    // ---- phase P: amortized hseq dump + poll tagged h_{t-1} + xp prefetch
    if (t > 0) {
      if ((t & 31) == 0 && tid >= 256) {
        const int idx = tid - 256, tt = idx >> 3, bb = idx & 7;
        short8 v = *(const short8*)&hhist[tt * 64 + bb * 8];
        *(short8*)(hseq + ((long)(bb * SEQ + (t - 32 + tt))) * HD + wg * NU) = v;
      }
      const int b = tid >> 6;
      const int k0 = (tid & 63) * 16;
      const unsigned tg = (unsigned)(tagbase + t - 1);
      const u64* s = (const u64*)(hxT + (((t - 1) & 1) << 13) + (b << 10) + k0);
      u64 qd[8];
      unsigned pend = 255u;
      do {
        u64 tmp[8];
#pragma unroll
        for (int j = 0; j < 8; ++j)
          if (pend & (1u << j))
            tmp[j] = __hip_atomic_load(s + j, __ATOMIC_RELAXED, __HIP_MEMORY_SCOPE_AGENT);
#pragma unroll
        for (int j = 0; j < 8; ++j)
          if (pend & (1u << j)) {
            unsigned t0 = ((unsigned)tmp[j]) >> 16;
            unsigned t1 = (unsigned)(tmp[j] >> 48);
            if ((t0 == tg) & (t1 == tg)) { qd[j] = tmp[j]; pend &= ~(1u << j); }
          }
      } while (pend);
      union { u16 a[16]; short8 v[2]; } pk;
#pragma unroll
      for (int j = 0; j < 8; ++j) {
        pk.a[2 * j]     = (u16)qd[j];
        pk.a[2 * j + 1] = (u16)(qd[j] >> 32);
      }
      const int ch = (tid & 63) * 2;
      *(short8*)&hA[b * 1024 + ((ch ^ (b & 7)) << 3)]       = pk.v[0];
      *(short8*)&hA[b * 1024 + (((ch + 1) ^ (b & 7)) << 3)] = pk.v[1];
    }
    if (tid >= 64 && tid < 96 && t + 1 < SEQ) {
      const int b = (tid - 64) >> 2, g = (tid - 64) & 3;
      short8 v = *(const short8*)(xp + ((long)((t + 1) * 8 + b) << 12) + g * HD + wg * NU);
#pragma unroll
      for (int u = 0; u < 8; ++u) xpf[(t + 1) & 1][b][g * 8 + u] = bf2f(((u16*)&v)[u]);
    }
    __syncthreads();

    // ---- phase B: MFMA, wave wid = ct*4 + kq; D[b][c] = sum_k h[b][k]*R_row(c)[k]
    {
      const int ct = wid >> 2, kq = wid & 3;
      f32x4 d = (f32x4){0.f, 0.f, 0.f, 0.f};
#pragma unroll
      for (int kk = 0; kk < 8; ++kk) {
        int chunk = kq * 32 + kk * 4 + q;
        short8 a = *(const short8*)&hA[r * 1024 + ((chunk ^ (r & 7)) << 3)];
        int c = ct * 16 + r;
        short8 b = *(const short8*)&wgt[c * 1024 + ((chunk ^ (c & 7)) << 3)];
        d = __builtin_amdgcn_mfma_f32_16x16x32_bf16(a, b, d, 0, 0, 0);
      }
#pragma unroll
      for (int rr = 0; rr < 4; ++rr)
        Dred[wid][(q * 4 + rr) * 16 + r] = d[rr];
    }
    __syncthreads();

    // ---- phase C: gates + state update (wave 0; lane = b*8+u)
    if (wid == 0) {
      const int b = lane >> 3, u = lane & 7;
      float pre[4];
#pragma unroll
      for (int g = 0; g < 4; ++g) {
        const int c = u * 4 + g;
        const int ctc = c >> 4, cc = c & 15;
        float s = xpf[t & 1][b][g * 8 + u];
#pragma unroll
        for (int k2 = 0; k2 < 4; ++k2) s += Dred[ctc * 4 + k2][b * 16 + cc];
        pre[g] = s;
      }
      float mn = fmaxf(pre[1] + m_s, pre[0]);
      float ig = __expf(pre[0] - mn);
      float fg = __expf(pre[1] + m_s - mn);
      c_s = fg * c_s + ig * tanhf(pre[2]);
      n_s = fg * n_s + ig;
      m_s = mn;
      float og = 1.0f / (1.0f + __expf(-pre[3]));
      float h = og * (c_s / n_s);

      unsigned hu = (unsigned)f2bf(h);
      hhist[(t & 31) * 64 + lane] = (u16)hu;           // stage for hseq dump
      if (t < SEQ - 1) {
        unsigned word = ((unsigned)(tagbase + t) << 16) | hu;
        __hip_atomic_store(hxT + ((t & 1) << 13) + (b << 10) + wg * NU + u, word,
                           __ATOMIC_RELAXED, __HIP_MEMORY_SCOPE_AGENT);
      }
    }
    __syncthreads();
  }

  // epilogue: dump last 32 steps (hhist rows 0..31 = steps 992..1023)
  if (tid >= 256) {
    const int idx = tid - 256, tt = idx >> 3, bb = idx & 7;
    short8 v = *(const short8*)&hhist[tt * 64 + bb * 8];
    *(short8*)(hseq + ((long)(bb * SEQ + (SEQ - 32 + tt))) * HD + wg * NU) = v;
  }
}

// ---------------- row LayerNorm (D=1024), fp32 out + bf16 copy ----------------
__global__ __launch_bounds__(256, 1) void k_ln(
    const float* __restrict__ z, const float* __restrict__ gamma, const float* __restrict__ beta,
    float* __restrict__ xout, u16* __restrict__ xb)
{
  const int row = blockIdx.x, tid = threadIdx.x;
  const float4 v = *(const float4*)(z + (long)row * HD + tid * 4);
  float s = v.x + v.y + v.z + v.w;
  float s2 = v.x * v.x + v.y * v.y + v.z * v.z + v.w * v.w;
#pragma unroll
  for (int off = 32; off > 0; off >>= 1) {
    s += __shfl_down(s, off, 64);
    s2 += __shfl_down(s2, off, 64);
  }
  __shared__ float red[8];
  const int wid = tid >> 6, lane = tid & 63;
  if (lane == 0) { red[wid] = s; red[4 + wid] = s2; }
  __syncthreads();
  float su = red[0] + red[1] + red[2] + red[3];
  float sq = red[4] + red[5] + red[6] + red[7];
  float mu = su * (1.f / 1024.f);
  float var = sq * (1.f / 1024.f) - mu * mu;
  float rs = rsqrtf(var + 1e-5f);
  const float4 g  = *(const float4*)(gamma + tid * 4);
  const float4 bt = *(const float4*)(beta + tid * 4);
  float4 o;
  o.x = (v.x - mu) * rs * g.x + bt.x;
  o.y = (v.y - mu) * rs * g.y + bt.y;
  o.z = (v.z - mu) * rs * g.z + bt.z;
  o.w = (v.w - mu) * rs * g.w + bt.w;
  *(float4*)(xout + (long)row * HD + tid * 4) = o;
  ushort4 ob;
  ob.x = f2bf(o.x); ob.y = f2bf(o.y); ob.z = f2bf(o.z); ob.w = f2bf(o.w);
  *(ushort4*)(xb + (long)row * HD + tid * 4) = ob;
}

// ---------------- launch ----------------
extern "C" void kernel_launch(void* const* d_in, const int* in_sizes, int n_in,
                              void* d_out, int out_size, void* d_ws, size_t ws_size,
                              hipStream_t stream)
{
  const float* input = (const float*)d_in[0];
  const float* W[2]  = { (const float*)d_in[1], (const float*)d_in[8] };
  const float* R[2]  = { (const float*)d_in[2], (const float*)d_in[9] };
  const float* bb[2] = { (const float*)d_in[3], (const float*)d_in[10] };
  const float* pW[2] = { (const float*)d_in[4], (const float*)d_in[11] };
  const float* pb[2] = { (const float*)d_in[5], (const float*)d_in[12] };
  const float* gm[2] = { (const float*)d_in[6], (const float*)d_in[13] };
  const float* bt[2] = { (const float*)d_in[7], (const float*)d_in[14] };
  float* out = (float*)d_out;

  char* p = (char*)d_ws;
  size_t off = 0;
  auto alloc = [&](size_t bytes) { char* q = p + off; off += (bytes + 255) & ~(size_t)255; return (void*)q; };
  uint32_t* hxT = (uint32_t*)alloc(2 * NB * HD * 4);   // tagged h words; never memset
  u16* xb     = (u16*)alloc((size_t)MROWS * HD * 2);
  u16* Wb[2]  = { (u16*)alloc((size_t)GD * HD * 2), (u16*)alloc((size_t)GD * HD * 2) };
  u16* Rbv[2] = { (u16*)alloc((size_t)GD * HD * 2), (u16*)alloc((size_t)GD * HD * 2) };
  u16* pWb[2] = { (u16*)alloc((size_t)HD * HD * 2), (u16*)alloc((size_t)HD * HD * 2) };
  u16* xpb    = (u16*)alloc((size_t)MROWS * GD * 2);
  u16* hs     = (u16*)alloc((size_t)MROWS * HD * 2);
  float* zb   = (float*)alloc((size_t)MROWS * HD * 4);
  float* x1   = (float*)alloc((size_t)MROWS * HD * 4);

  auto conv = [&](const float* src, u16* dst, long n) {
    int blocks = (int)((n / 4 + 255) / 256); if (blocks > 2048) blocks = 2048;
    k_tobf16<<<dim3(blocks), dim3(256), 0, stream>>>(src, dst, n);
  };
  conv(input, xb, (long)MROWS * HD);
  conv(W[0], Wb[0], (long)GD * HD);  conv(W[1], Wb[1], (long)GD * HD);
  conv(R[0], Rbv[0], (long)GD * HD); conv(R[1], Rbv[1], (long)GD * HD);
  conv(pW[0], pWb[0], (long)HD * HD); conv(pW[1], pWb[1], (long)HD * HD);

  for (int l = 0; l < 2; ++l) {
    // xp = x @ W.T + b  -> bf16, t-major layout
    k_gemm<0><<<dim3(GD / 128, MROWS / 128), 256, 0, stream>>>(
        xb, Wb[l], bb[l], nullptr, xpb, nullptr, GD, HD);
    // sLSTM scan (tag space disjoint per layer and per replay)
    k_scan<<<dim3(NWG), dim3(512), 0, stream>>>(xpb, Rbv[l], hs, hxT, l * 1024);
    // z = gelu(hseq @ pW.T + pb) + x_res
    const float* resp = (l == 0) ? input : x1;
    k_gemm<1><<<dim3(HD / 128, MROWS / 128), 256, 0, stream>>>(
        hs, pWb[l], pb[l], resp, nullptr, zb, HD, HD);
    // layernorm -> fp32 x_next (+ bf16 copy for next layer's GEMM1)
    float* xo = (l == 0) ? x1 : out;
    k_ln<<<dim3(MROWS), dim3(256), 0, stream>>>(zb, gm[l], bt[l], xo, xb);
  }
}

// Round 4
// 7346.169 us; speedup vs baseline: 1.2019x; 1.2019x over previous
//
#include <hip/hip_runtime.h>
#include <cstdint>
#include <cmath>

typedef unsigned short u16;
typedef unsigned long long u64;
typedef __attribute__((ext_vector_type(8))) short short8;
typedef __attribute__((ext_vector_type(4))) float f32x4;

#define SEQ 1024
#define HD 1024
#define GD 4096
#define NB 8
#define MROWS 8192   // NB*SEQ
#define NWG 128
#define NU 8         // hidden units per workgroup

__device__ __forceinline__ u16 f2bf(float f) {
  union { float f; uint32_t u; } c; c.f = f;
  uint32_t u = c.u;
  uint32_t r = (u + 0x7fffu + ((u >> 16) & 1u)) >> 16;
  return (u16)r;
}
__device__ __forceinline__ float bf2f(u16 h) {
  union { uint32_t u; float f; } c; c.u = ((uint32_t)h) << 16;
  return c.f;
}

// ---------------- fp32 -> bf16 convert ----------------
__global__ void k_tobf16(const float* __restrict__ in, u16* __restrict__ out, long n) {
  long i = ((long)blockIdx.x * 256L + threadIdx.x) * 4;
  long st = (long)gridDim.x * 1024L;
  for (; i < n; i += st) {
    float4 v = *(const float4*)(in + i);
    ushort4 o;
    o.x = f2bf(v.x); o.y = f2bf(v.y); o.z = f2bf(v.z); o.w = f2bf(v.w);
    *(ushort4*)(out + i) = o;
  }
}

// ---------------- bf16 MFMA GEMM: C[m][n] = sum_k A[m][k]*Bw[n][k] (+epilogue) ----
// MODE 0: outb[(t*8+b)*4096 + col] = bf16(acc + bias[n])   (t-major relayout for scan)
// MODE 1: outf = gelu(acc + bias[n]) + res[m][n]           (exact gelu)
template<int MODE>
__global__ __launch_bounds__(256, 1) void k_gemm(
    const u16* __restrict__ A, const u16* __restrict__ Bw,
    const float* __restrict__ bias, const float* __restrict__ res,
    u16* __restrict__ outb, float* __restrict__ outf, int N, int K)
{
  __shared__ u16 As[128][40];
  __shared__ u16 Bs[128][40];
  const int tid = threadIdx.x;
  const int wid = tid >> 6, lane = tid & 63;
  const int wm = wid >> 1, wn = wid & 1;
  const int r = lane & 15, q = lane >> 4;
  const long m0 = (long)blockIdx.y * 128, n0 = (long)blockIdx.x * 128;
  const int srow = tid >> 1, sseg = (tid & 1) * 16;

  f32x4 acc[4][4];
#pragma unroll
  for (int i = 0; i < 4; ++i)
#pragma unroll
    for (int j = 0; j < 4; ++j) acc[i][j] = (f32x4){0.f, 0.f, 0.f, 0.f};

  const u16* ag = A + (m0 + srow) * (long)K + sseg;
  const u16* bg = Bw + (n0 + srow) * (long)K + sseg;

  for (int k0 = 0; k0 < K; k0 += 32) {
    short8 av0 = *(const short8*)(ag + k0);
    short8 av1 = *(const short8*)(ag + k0 + 8);
    short8 bv0 = *(const short8*)(bg + k0);
    short8 bv1 = *(const short8*)(bg + k0 + 8);
    __syncthreads();
    *(short8*)&As[srow][sseg]     = av0;
    *(short8*)&As[srow][sseg + 8] = av1;
    *(short8*)&Bs[srow][sseg]     = bv0;
    *(short8*)&Bs[srow][sseg + 8] = bv1;
    __syncthreads();
    short8 bfr[4];
#pragma unroll
    for (int ni = 0; ni < 4; ++ni)
      bfr[ni] = *(const short8*)&Bs[wn * 64 + ni * 16 + r][q * 8];
#pragma unroll
    for (int mi = 0; mi < 4; ++mi) {
      short8 afr = *(const short8*)&As[wm * 64 + mi * 16 + r][q * 8];
#pragma unroll
      for (int ni = 0; ni < 4; ++ni)
        acc[mi][ni] = __builtin_amdgcn_mfma_f32_16x16x32_bf16(afr, bfr[ni], acc[mi][ni], 0, 0, 0);
    }
  }

#pragma unroll
  for (int mi = 0; mi < 4; ++mi)
#pragma unroll
    for (int ni = 0; ni < 4; ++ni) {
      long col = n0 + wn * 64 + ni * 16 + r;
      float bc = bias[col];
#pragma unroll
      for (int rr = 0; rr < 4; ++rr) {
        long row = m0 + wm * 64 + mi * 16 + q * 4 + rr;
        float v = acc[mi][ni][rr] + bc;
        if (MODE == 0) {
          long b = row >> 10, t = row & 1023;
          outb[((t * 8 + b) << 12) + col] = f2bf(v);
        } else {
          float ge = 0.5f * v * (1.0f + erff(v * 0.70710678118654752f));
          outf[row * N + col] = ge + res[row * N + col];
        }
      }
    }
}

// ---------------- persistent sLSTM scan (register-resident, 1 barrier/step) --
// 128 WGs x 512 threads, 1/CU. Wave roles:
//   waves 0-3 (kq): hold R-weight fragments in VGPRs; per epoch poll their
//     quarter's 32 flags, load h G2R (agent u64 loads), 16 MFMAs, Dred[par].
//   wave 4: gates + state + publish (hx store, vmcnt ack, flag).
//   wave 5: xp prefetch -> xpf ring (depth 4).
//   waves 6-7: amortized hseq dump every 32 steps (hhist 2 banks).
__global__ __launch_bounds__(512, 1) void k_scan(
    const u16* __restrict__ xp, const u16* __restrict__ Rb,
    u16* __restrict__ hseq, u16* __restrict__ hx, unsigned* __restrict__ flags,
    int tagbase)
{
  __shared__ float Dred[2][4][2][256];   // [par][kq][ct][m16*16 + n16]  (m=batch)
  __shared__ float xpf[4][NB][32];       // [par4][b][g*8+u]
  __shared__ u16 hhist[2][32][64];       // [bank][t&31][b*8+u]

  const int tid = threadIdx.x;
  const int wg = blockIdx.x;
  const int wid = tid >> 6, lane = tid & 63;
  const int r = lane & 15, q = lane >> 4;

  // ---- weights G2R (waves 0-3): wt[ct][kk] = R row c=ct*16+r, k=kq*256+kk*32+q*8
  short8 wt0[8], wt1[8];
  if (wid < 4) {
    const int kq = wid;
#pragma unroll
    for (int ct = 0; ct < 2; ++ct) {
      const int c = ct * 16 + r;
      const int uu = c >> 2, g = c & 3;
      const u16* src = Rb + ((long)(g * HD + wg * NU + uu)) * HD + kq * 256 + q * 8;
#pragma unroll
      for (int kk = 0; kk < 8; ++kk) {
        short8 v = *(const short8*)(src + kk * 32);
        if (ct == 0) wt0[kk] = v; else wt1[kk] = v;
      }
    }
  }
  // prologue: xpf[0] <- xp[t=0]
  if (wid == 5 && lane < 32) {
    const int b = lane >> 2, g = lane & 3;
    short8 v = *(const short8*)(xp + ((long)(0 * 8 + b) << 12) + g * HD + wg * NU);
#pragma unroll
    for (int u = 0; u < 8; ++u) xpf[0][b][g * 8 + u] = bf2f(((u16*)&v)[u]);
  }
  __syncthreads();

  float c_s = 0.f, n_s = 0.f, m_s = 0.f;

  for (int i = 0; i < SEQ; ++i) {
    if (wid < 4) {
      // prepare Dred for step i+1 (consume h_i, published this epoch)
      if (i + 1 < SEQ) {
        const int kq = wid;
        const unsigned tgt = (unsigned)(tagbase + i + 1);
        if (lane < 32) {
          while (__hip_atomic_load(&flags[(kq * 32 + lane) << 4],
                                   __ATOMIC_RELAXED, __HIP_MEMORY_SCOPE_AGENT) < tgt) {}
        }
        u64 lo[8], hi[8];
        if (r < 8) {
          const u64* src = (const u64*)hx + ((i & 1) << 11) + (r << 8) + kq * 64 + q * 2;
#pragma unroll
          for (int kk = 0; kk < 8; ++kk) {
            lo[kk] = __hip_atomic_load(src + kk * 8,     __ATOMIC_RELAXED, __HIP_MEMORY_SCOPE_AGENT);
            hi[kk] = __hip_atomic_load(src + kk * 8 + 1, __ATOMIC_RELAXED, __HIP_MEMORY_SCOPE_AGENT);
          }
        } else {
#pragma unroll
          for (int kk = 0; kk < 8; ++kk) { lo[kk] = 0; hi[kk] = 0; }
        }
        f32x4 a0 = (f32x4){0.f,0.f,0.f,0.f}, a1 = (f32x4){0.f,0.f,0.f,0.f};
#pragma unroll
        for (int kk = 0; kk < 8; ++kk) {
          union { u64 qv[2]; short8 v; } uu;
          uu.qv[0] = lo[kk]; uu.qv[1] = hi[kk];
          a0 = __builtin_amdgcn_mfma_f32_16x16x32_bf16(uu.v, wt0[kk], a0, 0, 0, 0);
          a1 = __builtin_amdgcn_mfma_f32_16x16x32_bf16(uu.v, wt1[kk], a1, 0, 0, 0);
        }
        const int par = (i + 1) & 1;
#pragma unroll
        for (int rr = 0; rr < 4; ++rr) {
          Dred[par][kq][0][(q * 4 + rr) * 16 + r] = a0[rr];   // [m=batch][n=c16]
          Dred[par][kq][1][(q * 4 + rr) * 16 + r] = a1[rr];
        }
      }
    } else if (wid == 4) {
      // gates + state for step i
      const int b = lane >> 3, u = lane & 7;
      float pre[4];
#pragma unroll
      for (int g = 0; g < 4; ++g) {
        float s = xpf[i & 3][b][g * 8 + u];
        if (i > 0) {
          const int c = u * 4 + g, ct = c >> 4, c16 = c & 15;
#pragma unroll
          for (int kq = 0; kq < 4; ++kq) s += Dred[i & 1][kq][ct][b * 16 + c16];
        }
        pre[g] = s;
      }
      float mn = fmaxf(pre[1] + m_s, pre[0]);
      float ig = __expf(pre[0] - mn);
      float fg = __expf(pre[1] + m_s - mn);
      float e2 = __expf(2.f * pre[2]);
      float th = 1.f - 2.f / (e2 + 1.f);          // tanh(pre[2])
      c_s = fg * c_s + ig * th;
      n_s = fg * n_s + ig;
      m_s = mn;
      float og = 1.f / (1.f + __expf(-pre[3]));
      float h = og * (c_s / n_s);

      unsigned hu = (unsigned)f2bf(h);
      hhist[(i >> 5) & 1][i & 31][lane] = (u16)hu;
      if (i < SEQ - 1) {
        unsigned lo2 = hu | (__shfl_down(hu, 1) << 16);
        u64 v64 = (u64)lo2 | ((u64)__shfl_down(lo2, 2) << 32);
        if ((lane & 3) == 0) {
          u64* dst = (u64*)hx + ((i & 1) << 11) + (b << 8) + ((wg * NU + u) >> 2);
          __hip_atomic_store(dst, v64, __ATOMIC_RELAXED, __HIP_MEMORY_SCOPE_AGENT);
        }
        asm volatile("s_waitcnt vmcnt(0)" ::: "memory");
        if (lane == 0)
          __hip_atomic_store(&flags[wg << 4], (unsigned)(tagbase + i + 1),
                             __ATOMIC_RELAXED, __HIP_MEMORY_SCOPE_AGENT);
      }
    } else if (wid == 5) {
      // prefetch xp[i+1] -> xpf[(i+1)&3]
      if (lane < 32 && i + 1 < SEQ) {
        const int b = lane >> 2, g = lane & 3;
        short8 v = *(const short8*)(xp + ((long)((i + 1) * 8 + b) << 12) + g * HD + wg * NU);
#pragma unroll
        for (int u = 0; u < 8; ++u) xpf[(i + 1) & 3][b][g * 8 + u] = bf2f(((u16*)&v)[u]);
      }
    } else {
      // waves 6-7: dump previous 32-step bank
      if (i > 0 && (i & 31) == 0) {
        const int idx = tid - 384;   // 0..127
#pragma unroll
        for (int j2 = 0; j2 < 2; ++j2) {
          int id = idx * 2 + j2, tt = id >> 3, bb = id & 7;
          short8 v = *(const short8*)&hhist[((i >> 5) & 1) ^ 1][tt][bb * 8];
          *(short8*)(hseq + ((long)(bb * SEQ + (i - 32 + tt))) * HD + wg * NU) = v;
        }
      }
    }
    __syncthreads();
  }

  // epilogue: dump last 32 steps (bank 1: steps 992..1023)
  if (wid >= 6) {
    const int idx = tid - 384;
#pragma unroll
    for (int j2 = 0; j2 < 2; ++j2) {
      int id = idx * 2 + j2, tt = id >> 3, bb = id & 7;
      short8 v = *(const short8*)&hhist[1][tt][bb * 8];
      *(short8*)(hseq + ((long)(bb * SEQ + (SEQ - 32 + tt))) * HD + wg * NU) = v;
    }
  }
}

// ---------------- row LayerNorm (D=1024), fp32 out + bf16 copy ----------------
__global__ __launch_bounds__(256, 1) void k_ln(
    const float* __restrict__ z, const float* __restrict__ gamma, const float* __restrict__ beta,
    float* __restrict__ xout, u16* __restrict__ xb)
{
  const int row = blockIdx.x, tid = threadIdx.x;
  const float4 v = *(const float4*)(z + (long)row * HD + tid * 4);
  float s = v.x + v.y + v.z + v.w;
  float s2 = v.x * v.x + v.y * v.y + v.z * v.z + v.w * v.w;
#pragma unroll
  for (int off = 32; off > 0; off >>= 1) {
    s += __shfl_down(s, off, 64);
    s2 += __shfl_down(s2, off, 64);
  }
  __shared__ float red[8];
  const int wid = tid >> 6, lane = tid & 63;
  if (lane == 0) { red[wid] = s; red[4 + wid] = s2; }
  __syncthreads();
  float su = red[0] + red[1] + red[2] + red[3];
  float sq = red[4] + red[5] + red[6] + red[7];
  float mu = su * (1.f / 1024.f);
  float var = sq * (1.f / 1024.f) - mu * mu;
  float rs = rsqrtf(var + 1e-5f);
  const float4 g  = *(const float4*)(gamma + tid * 4);
  const float4 bt = *(const float4*)(beta + tid * 4);
  float4 o;
  o.x = (v.x - mu) * rs * g.x + bt.x;
  o.y = (v.y - mu) * rs * g.y + bt.y;
  o.z = (v.z - mu) * rs * g.z + bt.z;
  o.w = (v.w - mu) * rs * g.w + bt.w;
  *(float4*)(xout + (long)row * HD + tid * 4) = o;
  ushort4 ob;
  ob.x = f2bf(o.x); ob.y = f2bf(o.y); ob.z = f2bf(o.z); ob.w = f2bf(o.w);
  *(ushort4*)(xb + (long)row * HD + tid * 4) = ob;
}

// ---------------- launch ----------------
extern "C" void kernel_launch(void* const* d_in, const int* in_sizes, int n_in,
                              void* d_out, int out_size, void* d_ws, size_t ws_size,
                              hipStream_t stream)
{
  const float* input = (const float*)d_in[0];
  const float* W[2]  = { (const float*)d_in[1], (const float*)d_in[8] };
  const float* R[2]  = { (const float*)d_in[2], (const float*)d_in[9] };
  const float* bb[2] = { (const float*)d_in[3], (const float*)d_in[10] };
  const float* pW[2] = { (const float*)d_in[4], (const float*)d_in[11] };
  const float* pb[2] = { (const float*)d_in[5], (const float*)d_in[12] };
  const float* gm[2] = { (const float*)d_in[6], (const float*)d_in[13] };
  const float* bt[2] = { (const float*)d_in[7], (const float*)d_in[14] };
  float* out = (float*)d_out;

  char* p = (char*)d_ws;
  size_t off = 0;
  auto alloc = [&](size_t bytes) { char* q = p + off; off += (bytes + 255) & ~(size_t)255; return (void*)q; };
  unsigned* flags = (unsigned*)alloc(NWG * 64);
  u16* hx     = (u16*)alloc(2 * NB * HD * 2);
  u16* xb     = (u16*)alloc((size_t)MROWS * HD * 2);
  u16* Wb[2]  = { (u16*)alloc((size_t)GD * HD * 2), (u16*)alloc((size_t)GD * HD * 2) };
  u16* Rbv[2] = { (u16*)alloc((size_t)GD * HD * 2), (u16*)alloc((size_t)GD * HD * 2) };
  u16* pWb[2] = { (u16*)alloc((size_t)HD * HD * 2), (u16*)alloc((size_t)HD * HD * 2) };
  u16* xpb    = (u16*)alloc((size_t)MROWS * GD * 2);
  u16* hs     = (u16*)alloc((size_t)MROWS * HD * 2);
  float* zb   = (float*)alloc((size_t)MROWS * HD * 4);
  float* x1   = (float*)alloc((size_t)MROWS * HD * 4);

  auto conv = [&](const float* src, u16* dst, long n) {
    int blocks = (int)((n / 4 + 255) / 256); if (blocks > 2048) blocks = 2048;
    k_tobf16<<<dim3(blocks), dim3(256), 0, stream>>>(src, dst, n);
  };
  conv(input, xb, (long)MROWS * HD);
  conv(W[0], Wb[0], (long)GD * HD);  conv(W[1], Wb[1], (long)GD * HD);
  conv(R[0], Rbv[0], (long)GD * HD); conv(R[1], Rbv[1], (long)GD * HD);
  conv(pW[0], pWb[0], (long)HD * HD); conv(pW[1], pWb[1], (long)HD * HD);

  // reset flags once per launch (tagbase keeps layers disjoint within a launch)
  hipMemsetAsync(flags, 0, NWG * 64, stream);

  for (int l = 0; l < 2; ++l) {
    // xp = x @ W.T + b  -> bf16, t-major layout
    k_gemm<0><<<dim3(GD / 128, MROWS / 128), 256, 0, stream>>>(
        xb, Wb[l], bb[l], nullptr, xpb, nullptr, GD, HD);
    // sLSTM scan
    k_scan<<<dim3(NWG), dim3(512), 0, stream>>>(xpb, Rbv[l], hs, hx, flags, l * 2048);
    // z = gelu(hseq @ pW.T + pb) + x_res
    const float* resp = (l == 0) ? input : x1;
    k_gemm<1><<<dim3(HD / 128, MROWS / 128), 256, 0, stream>>>(
        hs, pWb[l], pb[l], resp, nullptr, zb, HD, HD);
    // layernorm -> fp32 x_next (+ bf16 copy for next layer's GEMM1)
    float* xo = (l == 0) ? x1 : out;
    k_ln<<<dim3(MROWS), dim3(256), 0, stream>>>(zb, gm[l], bt[l], xo, xb);
  }
}